// Round 5
// baseline (165.894 us; speedup 1.0000x reference)
//
#include <hip/hip_runtime.h>
#include <math.h>

#define B_SZ   4
#define N_PTS  2048
#define EPSF   1e-6f

// ---- workspace float offsets ----
#define WS_KNN_R 0                       // 4*6144 real knn dists
#define WS_KNN_F 24576                   // 4*6144 fake knn dists
#define WS_FEAS  49152                   // 1024 feasibility partials (fake blocks)
#define WS_PSIP  50176                   // 1024 psi partials (fake blocks)
#define WS_RSUM  51200                   // 4 per-batch sum|r| (fake)
#define WS_Q     51204                   // 58 quantile outputs
#define QZF (WS_Q + 0)
#define QZR (WS_Q + 7)
#define QXF (WS_Q + 14)
#define QXR (WS_Q + 19)
#define QYF (WS_Q + 24)
#define QYR (WS_Q + 29)
#define QDR (WS_Q + 34)   // 4 batches x 3
#define QDF (WS_Q + 46)   // 4 batches x 3

__constant__ float c_qs7[7] = {0.05f, 0.1f, 0.25f, 0.5f, 0.75f, 0.9f, 0.95f};
__constant__ float c_qs5[5] = {0.05f, 0.25f, 0.5f, 0.75f, 0.95f};
__constant__ float c_qs3[3] = {0.05f, 0.5f, 0.95f};

#define CE(a, b) { float _lo = fminf(a, b), _hi = fmaxf(a, b); a = _lo; b = _hi; }

// branchless sorted-insert (ascending)
__device__ __forceinline__ void ins3a(float m[3], float v) {
    float h0 = fmaxf(m[0], v); m[0] = fminf(m[0], v);
    float h1 = fmaxf(m[1], h0); m[1] = fminf(m[1], h0);
    m[2] = fminf(m[2], h1);
}
__device__ __forceinline__ void ins5a(float m[5], float v) {
    float h0 = fmaxf(m[0], v); m[0] = fminf(m[0], v);
    float h1 = fmaxf(m[1], h0); m[1] = fminf(m[1], h0);
    float h2 = fmaxf(m[2], h1); m[2] = fminf(m[2], h1);
    float h3 = fmaxf(m[3], h2); m[3] = fminf(m[3], h2);
    m[4] = fminf(m[4], h3);
}

__device__ __forceinline__ unsigned int tokey(float f) {
    unsigned int u = __float_as_uint(f);
    return (u & 0x80000000u) ? ~u : (u | 0x80000000u);
}
__device__ __forceinline__ float fromkey(unsigned int k) {
    unsigned int u = (k & 0x80000000u) ? (k ^ 0x80000000u) : ~k;
    return __uint_as_float(u);
}

// ---------------- fused pair kernel ----------------
// blocks 0..1023  : fake clouds — knn + feasibility + hexatic (2 pts/wave)
// blocks 1024..1535: real clouds — knn only (4 pts/wave)
__global__ __launch_bounds__(256) void hs_pair_kernel(const float* __restrict__ real,
                                                      const float* __restrict__ fake,
                                                      float* __restrict__ ws) {
    __shared__ float2 sxy[N_PTS];
    __shared__ float sr[N_PTS];
    __shared__ float red[256];
    const int tid = threadIdx.x, wave = tid >> 6, lane = tid & 63;
    const int blk = blockIdx.x;

    if (blk < 1024) {
        // ---------- fake fused path (2 targets/wave) ----------
        const int b = blk >> 8, grp = blk & 255;
        const float* src = fake + (size_t)b * N_PTS * 3;
        for (int t = tid; t < N_PTS; t += 256) {
            const float* p = src + t * 3;
            sxy[t] = make_float2(p[0], p[1]);
            sr[t]  = fabsf(p[2]);
        }
        __syncthreads();
        const int p0 = grp * 8 + wave * 2;
        float px[2], py[2], pri[2], m[2][5];
#pragma unroll
        for (int t = 0; t < 2; ++t) {
            px[t] = sxy[p0 + t].x; py[t] = sxy[p0 + t].y;
            pri[t] = sr[p0 + t] - 1e-4f;
            m[t][0] = m[t][1] = m[t][2] = m[t][3] = m[t][4] = INFINITY;
        }
        // pass 1: squared-dist top-5 (incl self sq=0) + feasibility overlap
        float acc = 0.f;
        for (int j = lane; j < N_PTS; j += 64) {
            float2 q = sxy[j]; float br = sr[j];
#pragma unroll
            for (int t = 0; t < 2; ++t) {
                float dx = px[t] - q.x, dy = py[t] - q.y;
                float sq = fmaf(dx, dx, dy * dy);
                ins5a(m[t], sq);
                float ov = fmaxf((pri[t] + br) - sqrtf(sq), 0.f);
                acc += (sq > 0.f) ? ov : 0.f;
            }
        }
        // butterfly merge of sorted-5 lists
#pragma unroll
        for (int off = 1; off < 64; off <<= 1) {
#pragma unroll
            for (int t = 0; t < 2; ++t) {
                float b0 = __shfl_xor(m[t][0], off);
                float b1 = __shfl_xor(m[t][1], off);
                float b2 = __shfl_xor(m[t][2], off);
                float b3 = __shfl_xor(m[t][3], off);
                float b4 = __shfl_xor(m[t][4], off);
                float l0 = fminf(m[t][0], b4);
                float l1 = fminf(m[t][1], b3);
                float l2 = fminf(m[t][2], b2);
                float l3 = fminf(m[t][3], b1);
                float l4 = fminf(m[t][4], b0);
                CE(l0, l3); CE(l1, l4); CE(l0, l2); CE(l1, l3);
                CE(l0, l1); CE(l2, l4); CE(l1, l2); CE(l3, l4); CE(l2, l3);
                m[t][0] = l0; m[t][1] = l1; m[t][2] = l2; m[t][3] = l3; m[t][4] = l4;
            }
        }
        if (lane == 0) {
            float* kout = ws + WS_KNN_F + b * (N_PTS * 3);
#pragma unroll
            for (int t = 0; t < 2; ++t) {
                const int i = p0 + t;
                kout[i * 3 + 0] = sqrtf(m[t][0] + EPSF);
                kout[i * 3 + 1] = sqrtf(m[t][1] + EPSF);
                kout[i * 3 + 2] = sqrtf(m[t][2] + EPSF);
            }
        }
        float kth[2], invs[2];
#pragma unroll
        for (int t = 0; t < 2; ++t) {
            kth[t] = sqrtf(m[t][4] + EPSF);
            invs[t] = 1.f / fmaxf(0.1f * fmaxf(kth[t], EPSF), EPSF);
        }
        // pass 2: weighted e^{i4theta}
        float sw[2], sre[2], sim[2];
#pragma unroll
        for (int t = 0; t < 2; ++t) { sw[t] = 0.f; sre[t] = 0.f; sim[t] = 0.f; }
        for (int j = lane; j < N_PTS; j += 64) {
            float2 q = sxy[j];
#pragma unroll
            for (int t = 0; t < 2; ++t) {
                float dx = px[t] - q.x, dy = py[t] - q.y;
                float sq = fmaf(dx, dx, dy * dy);
                float dist = sqrtf(sq + EPSF);
                dist = (j == p0 + t) ? INFINITY : dist;
                float a = dx + ((fabsf(dx) < EPSF) ? EPSF : 0.f);
                float arg = fminf(fmaxf((kth[t] - dist) * invs[t], -50.f), 50.f);
                float e = __expf(-arg);
                float w = __builtin_amdgcn_rcpf(1.f + e);
                float aa = a * a, bb = dy * dy;
                float n2 = aa + bb;
                float z2r = aa - bb;
                float t0 = a * dy; float z2i = t0 + t0;
                float inv = __builtin_amdgcn_rcpf(n2);
                float ur = z2r * inv, ui = z2i * inv;
                float e4r = fmaf(ur, ur, -(ui * ui));
                float t1 = ur * ui; float e4i = t1 + t1;
                sw[t] += w;
                sre[t] = fmaf(w, e4r, sre[t]);
                sim[t] = fmaf(w, e4i, sim[t]);
            }
        }
#pragma unroll
        for (int off = 1; off < 64; off <<= 1) {
#pragma unroll
            for (int t = 0; t < 2; ++t) {
                sw[t]  += __shfl_xor(sw[t], off);
                sre[t] += __shfl_xor(sre[t], off);
                sim[t] += __shfl_xor(sim[t], off);
            }
        }
        float mypsi = 0.f;
        if (lane == 0) {
#pragma unroll
            for (int t = 0; t < 2; ++t) {
                float den = fmaxf(sw[t], EPSF);
                float pr = sre[t] / den, pi = sim[t] / den;
                mypsi += sqrtf(fmaf(pr, pr, pi * pi));
            }
        }
        // block reductions
        red[tid] = acc;
        __syncthreads();
        for (int s = 128; s > 0; s >>= 1) {
            if (tid < s) red[tid] += red[tid + s];
            __syncthreads();
        }
        if (tid == 0) ws[WS_FEAS + blk] = red[0];
        __syncthreads();
        red[tid] = (lane == 0) ? mypsi : 0.f;
        __syncthreads();
        for (int s = 128; s > 0; s >>= 1) {
            if (tid < s) red[tid] += red[tid + s];
            __syncthreads();
        }
        if (tid == 0) ws[WS_PSIP + blk] = red[0];
        if (grp == 0) {
            __syncthreads();
            float rs = 0.f;
            for (int t = tid; t < N_PTS; t += 256) rs += sr[t];
            red[tid] = rs;
            __syncthreads();
            for (int s = 128; s > 0; s >>= 1) {
                if (tid < s) red[tid] += red[tid + s];
                __syncthreads();
            }
            if (tid == 0) ws[WS_RSUM + b] = red[0];
        }
    } else {
        // ---------- real knn path (4 targets/wave) ----------
        const int rb = blk - 1024;
        const int b = rb >> 7, grp = rb & 127;
        const float* src = real + (size_t)b * N_PTS * 3;
        for (int t = tid; t < N_PTS; t += 256) {
            const float* p = src + t * 3;
            sxy[t] = make_float2(p[0], p[1]);
        }
        __syncthreads();
        const int p0 = grp * 16 + wave * 4;
        float px[4], py[4], m[4][3];
#pragma unroll
        for (int t = 0; t < 4; ++t) {
            px[t] = sxy[p0 + t].x; py[t] = sxy[p0 + t].y;
            m[t][0] = m[t][1] = m[t][2] = INFINITY;
        }
        for (int j = lane; j < N_PTS; j += 64) {
            float2 q = sxy[j];
#pragma unroll
            for (int t = 0; t < 4; ++t) {
                float dx = px[t] - q.x, dy = py[t] - q.y;
                float sq = fmaf(dx, dx, dy * dy);
                ins3a(m[t], sq);
            }
        }
#pragma unroll
        for (int off = 1; off < 64; off <<= 1) {
#pragma unroll
            for (int t = 0; t < 4; ++t) {
                float b0 = __shfl_xor(m[t][0], off);
                float b1 = __shfl_xor(m[t][1], off);
                float b2 = __shfl_xor(m[t][2], off);
                float l0 = fminf(m[t][0], b2);
                float l1 = fminf(m[t][1], b1);
                float l2 = fminf(m[t][2], b0);
                CE(l0, l1); CE(l0, l2); CE(l1, l2);
                m[t][0] = l0; m[t][1] = l1; m[t][2] = l2;
            }
        }
        if (lane == 0) {
            float* kout = ws + WS_KNN_R + b * (N_PTS * 3);
#pragma unroll
            for (int t = 0; t < 4; ++t) {
                const int i = p0 + t;
                kout[i * 3 + 0] = sqrtf(m[t][0] + EPSF);
                kout[i * 3 + 1] = sqrtf(m[t][1] + EPSF);
                kout[i * 3 + 2] = sqrtf(m[t][2] + EPSF);
            }
        }
    }
}

// ---------------- exact quantile: single-wave 8-bit radix select ----------------
// 58 blocks x 64 threads, 1 block per (array, q). Keys staged in LDS;
// histogram uses 8-way replicated bins to kill same-address atomic serialization.
__global__ __launch_bounds__(64) void hs_select_kernel(const float* __restrict__ real,
                                                       const float* __restrict__ fake,
                                                       float* __restrict__ ws) {
    __shared__ unsigned int skey[8192];
    __shared__ unsigned int hist[2048];   // 256 bins x 8 replicas
    const int lane = threadIdx.x;
    const int jb = blockIdx.x;

    const float* src; int step, n, slot; float q;
    if (jb < 34) {
        int aid, qi;
        if (jb < 7)       { aid = 0; qi = jb; }
        else if (jb < 14) { aid = 1; qi = jb - 7; }
        else              { aid = 2 + (jb - 14) / 5; qi = (jb - 14) % 5; }
        const float* base = (aid & 1) ? real : fake;
        const int c = (aid < 2) ? 2 : ((aid < 4) ? 0 : 1);
        src = base + c; step = 3; n = 8192;
        q = (aid < 2) ? c_qs7[qi] : c_qs5[qi];
        slot = ((aid == 0) ? QZF : (aid == 1) ? QZR : (aid == 2) ? QXF
              : (aid == 3) ? QXR : (aid == 4) ? QYF : QYR) + qi;
    } else {
        const int a = jb - 34;            // 0..23
        const int side = a / 12;          // 0 real, 1 fake
        const int b = (a % 12) / 3, qi = a % 3;
        src = ws + (side ? WS_KNN_F : WS_KNN_R) + b * (N_PTS * 3);
        step = 1; n = N_PTS * 3;
        q = c_qs3[qi];
        slot = (side ? QDF : QDR) + b * 3 + qi;
    }

    // stage sort-keys into LDS (pad with max-key)
#pragma unroll 4
    for (int it = 0; it < 128; ++it) {
        const int e = it * 64 + lane;
        skey[e] = (e < n) ? tokey(src[(size_t)e * step]) : 0xFFFFFFFFu;
    }
    __syncthreads();

    const float pos = q * (float)(n - 1);
    const int k = (int)pos;
    const float frac = pos - (float)k;

    unsigned int prefix = 0u;
    unsigned int kk = (unsigned int)k;
    const unsigned int rep = (unsigned int)(lane & 7);
#pragma unroll
    for (int pass = 0; pass < 4; ++pass) {
        const int shift = 24 - 8 * pass;
        const unsigned int amask = (pass == 0) ? 0u : (pass == 1) ? 0xFF000000u
                                 : (pass == 2) ? 0xFFFF0000u : 0xFFFFFF00u;
        // zero hist
#pragma unroll
        for (int i = 0; i < 32; ++i) hist[i * 64 + lane] = 0u;
        __syncthreads();
        // build (replicated bins)
        for (int it = 0; it < 128; ++it) {
            const unsigned int key = skey[it * 64 + lane];
            if (((key ^ prefix) & amask) == 0u) {
                const unsigned int bin = (key >> shift) & 255u;
                atomicAdd(&hist[bin * 8u + rep], 1u);
            }
        }
        __syncthreads();
        // lane owns bins 4*lane..4*lane+3; sum replicas, wave scan, pick bin
        unsigned int c[4], psum = 0;
#pragma unroll
        for (int i = 0; i < 4; ++i) {
            const uint4* hp = (const uint4*)&hist[(lane * 4 + i) * 8];
            uint4 a = hp[0], b2 = hp[1];
            c[i] = a.x + a.y + a.z + a.w + b2.x + b2.y + b2.z + b2.w;
            psum += c[i];
        }
        unsigned int incl = psum;
#pragma unroll
        for (int off = 1; off < 64; off <<= 1) {
            unsigned int nb = (unsigned int)__shfl_up((int)incl, off);
            if (lane >= off) incl += nb;
        }
        const unsigned int excl = incl - psum;
        const bool has = (excl <= kk) && (kk < incl);
        unsigned long long bmask = __ballot(has);
        const int srcl = (int)__ffsll((long long)bmask) - 1;
        unsigned int bsel = 0, rsel = 0;
        if (has) {
            unsigned int cum = excl;
#pragma unroll
            for (int i = 0; i < 4; ++i) {
                if (kk >= cum && kk < cum + c[i]) { bsel = (unsigned int)(lane * 4 + i); rsel = kk - cum; }
                cum += c[i];
            }
        }
        bsel = (unsigned int)__shfl((int)bsel, srcl);
        rsel = (unsigned int)__shfl((int)rsel, srcl);
        prefix |= bsel << shift;
        kk = rsel;
        __syncthreads();
    }
    const unsigned int vk = prefix;

    // count_le(vk) + min key > vk (tie-safe k+1-th order stat); pads are > vk
    unsigned int cle = 0, mg = 0xFFFFFFFFu;
    const uint4* kp = (const uint4*)skey;
#pragma unroll 4
    for (int it = 0; it < 32; ++it) {
        uint4 v = kp[it * 64 + lane];
        cle += (v.x <= vk) ? 1u : 0u;
        cle += (v.y <= vk) ? 1u : 0u;
        cle += (v.z <= vk) ? 1u : 0u;
        cle += (v.w <= vk) ? 1u : 0u;
        if (v.x > vk && v.x < mg) mg = v.x;
        if (v.y > vk && v.y < mg) mg = v.y;
        if (v.z > vk && v.z < mg) mg = v.z;
        if (v.w > vk && v.w < mg) mg = v.w;
    }
#pragma unroll
    for (int off = 1; off < 64; off <<= 1) {
        cle += (unsigned int)__shfl_xor((int)cle, off);
        unsigned int om = (unsigned int)__shfl_xor((int)mg, off);
        mg = (om < mg) ? om : mg;
    }
    if (lane == 0) {
        const unsigned int vhi = (cle >= (unsigned int)(k + 2)) ? vk : mg;
        const float flo = fromkey(vk), fhi = fromkey(vhi);
        ws[slot] = flo + frac * (fhi - flo);
    }
}

// ---------------- final combine ----------------
__global__ __launch_bounds__(256) void hs_final_kernel(const float* __restrict__ fouts,
                                                       const float* __restrict__ ws,
                                                       float* __restrict__ out) {
    __shared__ float red[256];
    __shared__ float s_feas;
    const int tid = threadIdx.x;
    float fs = 0.f, ps = 0.f;
    for (int t = tid; t < 1024; t += 256) {
        fs += ws[WS_FEAS + t];
        ps += ws[WS_PSIP + t];
    }
    red[tid] = fs;
    __syncthreads();
    for (int s = 128; s > 0; s >>= 1) {
        if (tid < s) red[tid] += red[tid + s];
        __syncthreads();
    }
    if (tid == 0) s_feas = red[0];
    __syncthreads();
    red[tid] = ps;
    __syncthreads();
    for (int s = 128; s > 0; s >>= 1) {
        if (tid < s) red[tid] += red[tid + s];
        __syncthreads();
    }
    if (tid == 0) {
        float psi_sum = red[0];
        float rsum = ws[WS_RSUM + 0] + ws[WS_RSUM + 1] + ws[WS_RSUM + 2] + ws[WS_RSUM + 3];
        float loss = 0.f;
        // radius loss
        float sacc = 0.f;
        for (int q = 0; q < 7; ++q) { float d = ws[QZF + q] - ws[QZR + q]; sacc += d * d; }
        loss += sacc / 7.f;
        // physical feasibility: (ordered_sum/2) / (N * sum|r|)
        loss += (0.5f * s_feas) / ((float)N_PTS * rsum);
        // gan loss
        float g = 0.f;
        for (int b = 0; b < B_SZ; ++b) {
            float p = fouts[b];
            g += 0.9f * fmaxf(logf(p), -100.f) + 0.1f * fmaxf(logf(1.f - p), -100.f);
        }
        loss += -g / (float)B_SZ;
        // grid density loss
        float sx = 0.f, sy = 0.f;
        for (int q = 0; q < 5; ++q) {
            float dx = ws[QXF + q] - ws[QXR + q]; sx += dx * dx;
            float dy = ws[QYF + q] - ws[QYR + q]; sy += dy * dy;
        }
        loss += 0.5f * (sx / 5.f + sy / 5.f);
        // distance loss
        float sd = 0.f;
        for (int t = 0; t < 12; ++t) { float d = ws[QDF + t] - ws[QDR + t]; sd += d * d; }
        loss += sd / 12.f;
        // grid order loss
        loss += -psi_sum / (float)(B_SZ * N_PTS);
        out[0] = loss;
    }
}

extern "C" void kernel_launch(void* const* d_in, const int* in_sizes, int n_in,
                              void* d_out, int out_size, void* d_ws, size_t ws_size,
                              hipStream_t stream) {
    (void)in_sizes; (void)n_in; (void)out_size; (void)ws_size;
    const float* real  = (const float*)d_in[0];
    const float* fake  = (const float*)d_in[1];
    const float* fouts = (const float*)d_in[2];
    float* out = (float*)d_out;
    float* ws  = (float*)d_ws;

    hipLaunchKernelGGL(hs_pair_kernel,   dim3(1536), dim3(256), 0, stream, real, fake, ws);
    hipLaunchKernelGGL(hs_select_kernel, dim3(58),   dim3(64),  0, stream, real, fake, ws);
    hipLaunchKernelGGL(hs_final_kernel,  dim3(1),    dim3(256), 0, stream, fouts, ws, out);
}

// Round 6
// 133.181 us; speedup vs baseline: 1.2456x; 1.2456x over previous
//
#include <hip/hip_runtime.h>
#include <math.h>

#define B_SZ   4
#define N_PTS  2048
#define EPSF   1e-6f

// ---- workspace float offsets ----
#define WS_KNN_R 0                       // 4*6144 real knn dists
#define WS_KNN_F 24576                   // 4*6144 fake knn dists
#define WS_FEAS  49152                   // 1024 feasibility partials (fake blocks)
#define WS_PSIP  50176                   // 1024 psi partials (fake blocks)
#define WS_RSUM  51200                   // 4 per-batch sum|r| (fake)
#define WS_Q     51204                   // 58 quantile outputs
#define WS_CNT   51264                   // done-ticket counter (uint)
#define QZF (WS_Q + 0)
#define QZR (WS_Q + 7)
#define QXF (WS_Q + 14)
#define QXR (WS_Q + 19)
#define QYF (WS_Q + 24)
#define QYR (WS_Q + 29)
#define QDR (WS_Q + 34)   // 4 batches x 3
#define QDF (WS_Q + 46)   // 4 batches x 3

__constant__ float c_qs7[7] = {0.05f, 0.1f, 0.25f, 0.5f, 0.75f, 0.9f, 0.95f};
__constant__ float c_qs5[5] = {0.05f, 0.25f, 0.5f, 0.75f, 0.95f};
__constant__ float c_qs3[3] = {0.05f, 0.5f, 0.95f};

#define CE(a, b) { float _lo = fminf(a, b), _hi = fmaxf(a, b); a = _lo; b = _hi; }

// branchless sorted-insert (ascending)
__device__ __forceinline__ void ins3a(float m[3], float v) {
    float h0 = fmaxf(m[0], v); m[0] = fminf(m[0], v);
    float h1 = fmaxf(m[1], h0); m[1] = fminf(m[1], h0);
    m[2] = fminf(m[2], h1);
}
__device__ __forceinline__ void ins5a(float m[5], float v) {
    float h0 = fmaxf(m[0], v); m[0] = fminf(m[0], v);
    float h1 = fmaxf(m[1], h0); m[1] = fminf(m[1], h0);
    float h2 = fmaxf(m[2], h1); m[2] = fminf(m[2], h1);
    float h3 = fmaxf(m[3], h2); m[3] = fminf(m[3], h2);
    m[4] = fminf(m[4], h3);
}

__device__ __forceinline__ unsigned int tokey(float f) {
    unsigned int u = __float_as_uint(f);
    return (u & 0x80000000u) ? ~u : (u | 0x80000000u);
}
__device__ __forceinline__ float fromkey(unsigned int k) {
    unsigned int u = (k & 0x80000000u) ? (k ^ 0x80000000u) : ~k;
    return __uint_as_float(u);
}

// ---------------- fused pair kernel (unchanged from R4 except ticket zero) ----------------
// blocks 0..1023  : fake clouds — knn + feasibility + hexatic (2 pts/wave)
// blocks 1024..1535: real clouds — knn only (4 pts/wave)
__global__ __launch_bounds__(256) void hs_pair_kernel(const float* __restrict__ real,
                                                      const float* __restrict__ fake,
                                                      float* __restrict__ ws) {
    __shared__ float2 sxy[N_PTS];
    __shared__ float sr[N_PTS];
    __shared__ float red[256];
    const int tid = threadIdx.x, wave = tid >> 6, lane = tid & 63;
    const int blk = blockIdx.x;
    if (blk == 0 && tid == 0) ((unsigned int*)ws)[WS_CNT] = 0u;   // zero done-ticket

    if (blk < 1024) {
        // ---------- fake fused path (2 targets/wave) ----------
        const int b = blk >> 8, grp = blk & 255;
        const float* src = fake + (size_t)b * N_PTS * 3;
        for (int t = tid; t < N_PTS; t += 256) {
            const float* p = src + t * 3;
            sxy[t] = make_float2(p[0], p[1]);
            sr[t]  = fabsf(p[2]);
        }
        __syncthreads();
        const int p0 = grp * 8 + wave * 2;
        float px[2], py[2], pri[2], m[2][5];
#pragma unroll
        for (int t = 0; t < 2; ++t) {
            px[t] = sxy[p0 + t].x; py[t] = sxy[p0 + t].y;
            pri[t] = sr[p0 + t] - 1e-4f;
            m[t][0] = m[t][1] = m[t][2] = m[t][3] = m[t][4] = INFINITY;
        }
        float acc = 0.f;
        for (int j = lane; j < N_PTS; j += 64) {
            float2 q = sxy[j]; float br = sr[j];
#pragma unroll
            for (int t = 0; t < 2; ++t) {
                float dx = px[t] - q.x, dy = py[t] - q.y;
                float sq = fmaf(dx, dx, dy * dy);
                ins5a(m[t], sq);
                float ov = fmaxf((pri[t] + br) - sqrtf(sq), 0.f);
                acc += (sq > 0.f) ? ov : 0.f;
            }
        }
#pragma unroll
        for (int off = 1; off < 64; off <<= 1) {
#pragma unroll
            for (int t = 0; t < 2; ++t) {
                float b0 = __shfl_xor(m[t][0], off);
                float b1 = __shfl_xor(m[t][1], off);
                float b2 = __shfl_xor(m[t][2], off);
                float b3 = __shfl_xor(m[t][3], off);
                float b4 = __shfl_xor(m[t][4], off);
                float l0 = fminf(m[t][0], b4);
                float l1 = fminf(m[t][1], b3);
                float l2 = fminf(m[t][2], b2);
                float l3 = fminf(m[t][3], b1);
                float l4 = fminf(m[t][4], b0);
                CE(l0, l3); CE(l1, l4); CE(l0, l2); CE(l1, l3);
                CE(l0, l1); CE(l2, l4); CE(l1, l2); CE(l3, l4); CE(l2, l3);
                m[t][0] = l0; m[t][1] = l1; m[t][2] = l2; m[t][3] = l3; m[t][4] = l4;
            }
        }
        if (lane == 0) {
            float* kout = ws + WS_KNN_F + b * (N_PTS * 3);
#pragma unroll
            for (int t = 0; t < 2; ++t) {
                const int i = p0 + t;
                kout[i * 3 + 0] = sqrtf(m[t][0] + EPSF);
                kout[i * 3 + 1] = sqrtf(m[t][1] + EPSF);
                kout[i * 3 + 2] = sqrtf(m[t][2] + EPSF);
            }
        }
        float kth[2], invs[2];
#pragma unroll
        for (int t = 0; t < 2; ++t) {
            kth[t] = sqrtf(m[t][4] + EPSF);
            invs[t] = 1.f / fmaxf(0.1f * fmaxf(kth[t], EPSF), EPSF);
        }
        float sw[2], sre[2], sim[2];
#pragma unroll
        for (int t = 0; t < 2; ++t) { sw[t] = 0.f; sre[t] = 0.f; sim[t] = 0.f; }
        for (int j = lane; j < N_PTS; j += 64) {
            float2 q = sxy[j];
#pragma unroll
            for (int t = 0; t < 2; ++t) {
                float dx = px[t] - q.x, dy = py[t] - q.y;
                float sq = fmaf(dx, dx, dy * dy);
                float dist = sqrtf(sq + EPSF);
                dist = (j == p0 + t) ? INFINITY : dist;
                float a = dx + ((fabsf(dx) < EPSF) ? EPSF : 0.f);
                float arg = fminf(fmaxf((kth[t] - dist) * invs[t], -50.f), 50.f);
                float e = __expf(-arg);
                float w = __builtin_amdgcn_rcpf(1.f + e);
                float aa = a * a, bb = dy * dy;
                float n2 = aa + bb;
                float z2r = aa - bb;
                float t0 = a * dy; float z2i = t0 + t0;
                float inv = __builtin_amdgcn_rcpf(n2);
                float ur = z2r * inv, ui = z2i * inv;
                float e4r = fmaf(ur, ur, -(ui * ui));
                float t1 = ur * ui; float e4i = t1 + t1;
                sw[t] += w;
                sre[t] = fmaf(w, e4r, sre[t]);
                sim[t] = fmaf(w, e4i, sim[t]);
            }
        }
#pragma unroll
        for (int off = 1; off < 64; off <<= 1) {
#pragma unroll
            for (int t = 0; t < 2; ++t) {
                sw[t]  += __shfl_xor(sw[t], off);
                sre[t] += __shfl_xor(sre[t], off);
                sim[t] += __shfl_xor(sim[t], off);
            }
        }
        float mypsi = 0.f;
        if (lane == 0) {
#pragma unroll
            for (int t = 0; t < 2; ++t) {
                float den = fmaxf(sw[t], EPSF);
                float pr = sre[t] / den, pi = sim[t] / den;
                mypsi += sqrtf(fmaf(pr, pr, pi * pi));
            }
        }
        red[tid] = acc;
        __syncthreads();
        for (int s = 128; s > 0; s >>= 1) {
            if (tid < s) red[tid] += red[tid + s];
            __syncthreads();
        }
        if (tid == 0) ws[WS_FEAS + blk] = red[0];
        __syncthreads();
        red[tid] = (lane == 0) ? mypsi : 0.f;
        __syncthreads();
        for (int s = 128; s > 0; s >>= 1) {
            if (tid < s) red[tid] += red[tid + s];
            __syncthreads();
        }
        if (tid == 0) ws[WS_PSIP + blk] = red[0];
        if (grp == 0) {
            __syncthreads();
            float rs = 0.f;
            for (int t = tid; t < N_PTS; t += 256) rs += sr[t];
            red[tid] = rs;
            __syncthreads();
            for (int s = 128; s > 0; s >>= 1) {
                if (tid < s) red[tid] += red[tid + s];
                __syncthreads();
            }
            if (tid == 0) ws[WS_RSUM + b] = red[0];
        }
    } else {
        // ---------- real knn path (4 targets/wave) ----------
        const int rb = blk - 1024;
        const int b = rb >> 7, grp = rb & 127;
        const float* src = real + (size_t)b * N_PTS * 3;
        for (int t = tid; t < N_PTS; t += 256) {
            const float* p = src + t * 3;
            sxy[t] = make_float2(p[0], p[1]);
        }
        __syncthreads();
        const int p0 = grp * 16 + wave * 4;
        float px[4], py[4], m[4][3];
#pragma unroll
        for (int t = 0; t < 4; ++t) {
            px[t] = sxy[p0 + t].x; py[t] = sxy[p0 + t].y;
            m[t][0] = m[t][1] = m[t][2] = INFINITY;
        }
        for (int j = lane; j < N_PTS; j += 64) {
            float2 q = sxy[j];
#pragma unroll
            for (int t = 0; t < 4; ++t) {
                float dx = px[t] - q.x, dy = py[t] - q.y;
                float sq = fmaf(dx, dx, dy * dy);
                ins3a(m[t], sq);
            }
        }
#pragma unroll
        for (int off = 1; off < 64; off <<= 1) {
#pragma unroll
            for (int t = 0; t < 4; ++t) {
                float b0 = __shfl_xor(m[t][0], off);
                float b1 = __shfl_xor(m[t][1], off);
                float b2 = __shfl_xor(m[t][2], off);
                float l0 = fminf(m[t][0], b2);
                float l1 = fminf(m[t][1], b1);
                float l2 = fminf(m[t][2], b0);
                CE(l0, l1); CE(l0, l2); CE(l1, l2);
                m[t][0] = l0; m[t][1] = l1; m[t][2] = l2;
            }
        }
        if (lane == 0) {
            float* kout = ws + WS_KNN_R + b * (N_PTS * 3);
#pragma unroll
            for (int t = 0; t < 4; ++t) {
                const int i = p0 + t;
                kout[i * 3 + 0] = sqrtf(m[t][0] + EPSF);
                kout[i * 3 + 1] = sqrtf(m[t][1] + EPSF);
                kout[i * 3 + 2] = sqrtf(m[t][2] + EPSF);
            }
        }
    }
}

// ---------------- exact quantile radix select + fused final ----------------
// 58 blocks x 1024 threads (16 waves). 8 keys/thread in registers.
// 4 passes x 8-bit digits; hist[wave][bin][lane&1] (32 KB) — per-wave regions,
// 2 lane-replicas, only 8 atomic rounds/pass. Last block does the final combine.
__global__ __launch_bounds__(1024) void hs_select_kernel(const float* __restrict__ real,
                                                         const float* __restrict__ fake,
                                                         const float* __restrict__ fouts,
                                                         float* __restrict__ ws,
                                                         float* __restrict__ out) {
    __shared__ unsigned int hist[16][256][2];   // 32 KB
    __shared__ unsigned int s_bin, s_rank;
    __shared__ unsigned int s_part[16], s_min[16];
    __shared__ float sred[1024];
    __shared__ int s_last;
    const int tid = threadIdx.x, wave = tid >> 6, lane = tid & 63;
    const int jb = blockIdx.x;

    const float* src; int step, n, slot; float q;
    if (jb < 34) {
        int aid, qi;
        if (jb < 7)       { aid = 0; qi = jb; }
        else if (jb < 14) { aid = 1; qi = jb - 7; }
        else              { aid = 2 + (jb - 14) / 5; qi = (jb - 14) % 5; }
        const float* base = (aid & 1) ? real : fake;
        const int c = (aid < 2) ? 2 : ((aid < 4) ? 0 : 1);
        src = base + c; step = 3; n = 8192;
        q = (aid < 2) ? c_qs7[qi] : c_qs5[qi];
        slot = ((aid == 0) ? QZF : (aid == 1) ? QZR : (aid == 2) ? QXF
              : (aid == 3) ? QXR : (aid == 4) ? QYF : QYR) + qi;
    } else {
        const int a = jb - 34;            // 0..23
        const int side = a / 12;          // 0 real, 1 fake
        const int b = (a % 12) / 3, qi = a % 3;
        src = ws + (side ? WS_KNN_F : WS_KNN_R) + b * (N_PTS * 3);
        step = 1; n = N_PTS * 3;
        q = c_qs3[qi];
        slot = (side ? QDF : QDR) + b * 3 + qi;
    }

    unsigned int rr[8];
#pragma unroll
    for (int u = 0; u < 8; ++u) {
        const int e = u * 1024 + tid;
        rr[u] = (e < n) ? tokey(src[(size_t)e * step]) : 0xFFFFFFFFu;
    }

    const float pos = q * (float)(n - 1);
    const int k = (int)pos;
    const float frac = pos - (float)k;

    unsigned int prefix = 0u;
    unsigned int kk = (unsigned int)k;
    const unsigned int rep = (unsigned int)(lane & 1);
#pragma unroll
    for (int pass = 0; pass < 4; ++pass) {
        const int shift = 24 - 8 * pass;
        const unsigned int amask = (pass == 0) ? 0u : (pass == 1) ? 0xFF000000u
                                 : (pass == 2) ? 0xFFFF0000u : 0xFFFFFF00u;
        // zero hist: 8192 uints / 1024 threads
        unsigned int* hflat = &hist[0][0][0];
#pragma unroll
        for (int i = 0; i < 8; ++i) hflat[i * 1024 + tid] = 0u;
        __syncthreads();
        // build: 8 rounds, per-wave regions, 2 lane-replicas
#pragma unroll
        for (int u = 0; u < 8; ++u) {
            const unsigned int key = rr[u];
            if (((key ^ prefix) & amask) == 0u)
                atomicAdd(&hist[wave][(key >> shift) & 255u][rep], 1u);
        }
        __syncthreads();
        // wave 0: sum replicas/waves, scan 256 bins (4/lane), pick bucket
        if (tid < 64) {
            unsigned int c[4], ps = 0;
#pragma unroll
            for (int i = 0; i < 4; ++i) {
                unsigned int s = 0;
                const int bin = lane * 4 + i;
#pragma unroll
                for (int w = 0; w < 16; ++w) {
                    uint2 v = *(const uint2*)&hist[w][bin][0];
                    s += v.x + v.y;
                }
                c[i] = s; ps += s;
            }
            unsigned int incl = ps;
#pragma unroll
            for (int off = 1; off < 64; off <<= 1) {
                unsigned int nb = (unsigned int)__shfl_up((int)incl, off);
                if (lane >= off) incl += nb;
            }
            const unsigned int excl = incl - ps;
            if (excl <= kk && kk < incl) {     // exactly one lane
                unsigned int cum = excl;
#pragma unroll
                for (int i = 0; i < 4; ++i) {
                    if (kk < cum + c[i]) { s_bin = (unsigned int)(lane * 4 + i); s_rank = kk - cum; break; }
                    cum += c[i];
                }
            }
        }
        __syncthreads();
        prefix |= s_bin << shift;
        kk = s_rank;
    }
    const unsigned int vk = prefix;

    // count_le(vk) + min key > vk (tie-safe k+1-th order stat); pads (max-key) are > vk
    unsigned int cle = 0, mg = 0xFFFFFFFFu;
#pragma unroll
    for (int u = 0; u < 8; ++u) {
        cle += (rr[u] <= vk) ? 1u : 0u;
        if (rr[u] > vk && rr[u] < mg) mg = rr[u];
    }
#pragma unroll
    for (int off = 1; off < 64; off <<= 1) {
        cle += (unsigned int)__shfl_xor((int)cle, off);
        unsigned int om = (unsigned int)__shfl_xor((int)mg, off);
        mg = (om < mg) ? om : mg;
    }
    if (lane == 0) { s_part[wave] = cle; s_min[wave] = mg; }
    __syncthreads();
    if (tid == 0) {
        unsigned int tot = 0, mga = 0xFFFFFFFFu;
#pragma unroll
        for (int w = 0; w < 16; ++w) {
            tot += s_part[w];
            if (s_min[w] < mga) mga = s_min[w];
        }
        const unsigned int vhi = (tot >= (unsigned int)(k + 2)) ? vk : mga;
        const float flo = fromkey(vk), fhi = fromkey(vhi);
        ws[slot] = flo + frac * (fhi - flo);
    }

    // ---- last-block-done: fused final combine ----
    __threadfence();
    if (tid == 0) {
        unsigned int t = atomicAdd(&((unsigned int*)ws)[WS_CNT], 1u);
        s_last = (t == 57u) ? 1 : 0;
    }
    __syncthreads();
    if (!s_last) return;
    __threadfence();

    float fs = ws[WS_FEAS + tid];
    float ps = ws[WS_PSIP + tid];
    sred[tid] = fs;
    __syncthreads();
    for (int s = 512; s > 0; s >>= 1) {
        if (tid < s) sred[tid] += sred[tid + s];
        __syncthreads();
    }
    float s_feas = sred[0];
    __syncthreads();
    sred[tid] = ps;
    __syncthreads();
    for (int s = 512; s > 0; s >>= 1) {
        if (tid < s) sred[tid] += sred[tid + s];
        __syncthreads();
    }
    if (tid == 0) {
        float psi_sum = sred[0];
        float rsum = ws[WS_RSUM + 0] + ws[WS_RSUM + 1] + ws[WS_RSUM + 2] + ws[WS_RSUM + 3];
        float loss = 0.f;
        // radius loss
        float sacc = 0.f;
        for (int qq = 0; qq < 7; ++qq) { float d = ws[QZF + qq] - ws[QZR + qq]; sacc += d * d; }
        loss += sacc / 7.f;
        // physical feasibility: (ordered_sum/2) / (N * sum|r|)
        loss += (0.5f * s_feas) / ((float)N_PTS * rsum);
        // gan loss
        float g = 0.f;
        for (int b = 0; b < B_SZ; ++b) {
            float p = fouts[b];
            g += 0.9f * fmaxf(logf(p), -100.f) + 0.1f * fmaxf(logf(1.f - p), -100.f);
        }
        loss += -g / (float)B_SZ;
        // grid density loss
        float sx = 0.f, sy = 0.f;
        for (int qq = 0; qq < 5; ++qq) {
            float dx = ws[QXF + qq] - ws[QXR + qq]; sx += dx * dx;
            float dy = ws[QYF + qq] - ws[QYR + qq]; sy += dy * dy;
        }
        loss += 0.5f * (sx / 5.f + sy / 5.f);
        // distance loss
        float sd = 0.f;
        for (int t = 0; t < 12; ++t) { float d = ws[QDF + t] - ws[QDR + t]; sd += d * d; }
        loss += sd / 12.f;
        // grid order loss
        loss += -psi_sum / (float)(B_SZ * N_PTS);
        out[0] = loss;
    }
}

extern "C" void kernel_launch(void* const* d_in, const int* in_sizes, int n_in,
                              void* d_out, int out_size, void* d_ws, size_t ws_size,
                              hipStream_t stream) {
    (void)in_sizes; (void)n_in; (void)out_size; (void)ws_size;
    const float* real  = (const float*)d_in[0];
    const float* fake  = (const float*)d_in[1];
    const float* fouts = (const float*)d_in[2];
    float* out = (float*)d_out;
    float* ws  = (float*)d_ws;

    hipLaunchKernelGGL(hs_pair_kernel,   dim3(1536), dim3(256),  0, stream, real, fake, ws);
    hipLaunchKernelGGL(hs_select_kernel, dim3(58),   dim3(1024), 0, stream, real, fake, fouts, ws, out);
}